// Round 15
// baseline (453.779 us; speedup 1.0000x reference)
//
#include <hip/hip_runtime.h>
#include <hip/hip_bf16.h>

#define D 128
#define CAP_R 128   // max rows per bin (rows = 2*matches; mean 32.8, 128 = ~12 sigma)

// ---------------- fallback (round-1) kernel ----------------
__global__ __launch_bounds__(256) void transe_time_kernel(
    const int* __restrict__ idx, const float* __restrict__ ent,
    const float* __restrict__ rel, const float* __restrict__ tt,
    float* __restrict__ out, int B)
{
    const int b = blockIdx.x;
    if (b >= B) return;
    const int tid = threadIdx.x;
    const int e4  = tid & 31;
    const int g   = tid >> 5;

    __shared__ float sh_h[D];
    __shared__ float sh_t[D];
    __shared__ float ph[8][D];
    __shared__ float pt[8][D];
    __shared__ float wred[8];

    const int hi = idx[b * 5 + 0];
    const int ri = idx[b * 5 + 1];
    const int ti = idx[b * 5 + 2];
    const int si = idx[b * 5 + 3];
    const int ei = idx[b * 5 + 4];

    if (tid < D) {
        sh_h[tid] = ent[(size_t)hi * D + tid];
        sh_t[tid] = ent[(size_t)ti * D + tid];
    }
    __syncthreads();

    const float4* __restrict__ Ts = (const float4*)(tt + (size_t)si * D * D);
    const float4* __restrict__ Te = (const float4*)(tt + (size_t)ei * D * D);

    float4 hacc = make_float4(0.f, 0.f, 0.f, 0.f);
    float4 tacc = make_float4(0.f, 0.f, 0.f, 0.f);

    #pragma unroll 4
    for (int d0 = 0; d0 < D; d0 += 8) {
        const int d = d0 + g;
        const float4 a = Ts[d * 32 + e4];
        const float4 c = Te[d * 32 + e4];
        const float hd = sh_h[d];
        const float td = sh_t[d];
        const float mx = a.x + c.x;
        const float my = a.y + c.y;
        const float mz = a.z + c.z;
        const float mw = a.w + c.w;
        hacc.x += hd * mx; hacc.y += hd * my; hacc.z += hd * mz; hacc.w += hd * mw;
        tacc.x += td * mx; tacc.y += td * my; tacc.z += td * mz; tacc.w += td * mw;
    }

    ((float4*)ph[g])[e4] = hacc;
    ((float4*)pt[g])[e4] = tacc;
    __syncthreads();

    float h2 = 0.f, t2 = 0.f;
    if (tid < D) {
        #pragma unroll
        for (int k = 0; k < 8; ++k) { h2 += ph[k][tid]; t2 += pt[k][tid]; }
    }
    float nh = h2 * h2;
    float nt = t2 * t2;
    #pragma unroll
    for (int off = 32; off; off >>= 1) {
        nh += __shfl_down(nh, off, 64);
        nt += __shfl_down(nt, off, 64);
    }
    const int wv = tid >> 6;
    if ((tid & 63) == 0) { wred[wv * 2] = nh; wred[wv * 2 + 1] = nt; }
    __syncthreads();
    const float NH = wred[0] + wred[2] + wred[4] + wred[6];
    const float NT2 = wred[1] + wred[3] + wred[5] + wred[7];
    const float rnh = 1.0f / fmaxf(sqrtf(NH), 1e-12f);
    const float rnt = 1.0f / fmaxf(sqrtf(NT2), 1e-12f);

    float v = 0.f;
    if (tid < D) {
        const float rr = rel[(size_t)ri * D + tid];
        v = fabsf(h2 * rnh + rr - t2 * rnt + 1e-6f);
    }
    #pragma unroll
    for (int off = 32; off; off >>= 1) v += __shfl_down(v, off, 64);
    __syncthreads();
    if ((tid & 63) == 0) wred[wv] = v;
    __syncthreads();
    if (tid == 0) out[b] = wred[0] + wred[1] + wred[2] + wred[3];
}

// ---------------- pipeline: zero -> scatter -> fused matvec+score ----------

__global__ __launch_bounds__(1024) void zero_kernel(
    int* __restrict__ cnt, int* __restrict__ done, int NT, int B)
{
    const int i = blockIdx.x * 1024 + threadIdx.x;
    if (i < NT) cnt[i] = 0;
    if (i >= NT && i < NT + B) done[i - NT] = 0;
}

// rows[u*CAP_R + p] = {eid, y}, y = b*4 + ht*2 + slot
__global__ __launch_bounds__(256) void scatter_kernel(
    const int* __restrict__ idx, int* __restrict__ cnt,
    int2* __restrict__ rowsbuf, int B)
{
    const int i = blockIdx.x * blockDim.x + threadIdx.x;
    const int stride = gridDim.x * blockDim.x;
    for (int b = i; b < B; b += stride) {
        const int h_eid = idx[b * 5 + 0];
        const int t_eid = idx[b * 5 + 2];
        #pragma unroll
        for (int slot = 0; slot < 2; ++slot) {
            const int u = idx[b * 5 + 3 + slot];
            const int p = atomicAdd(&cnt[u], 2);
            if (p + 1 < CAP_R) {
                rowsbuf[u * CAP_R + p]     = make_int2(h_eid, b * 4 + 0 + slot);
                rowsbuf[u * CAP_R + p + 1] = make_int2(t_eid, b * 4 + 2 + slot);
            }
        }
    }
}

__device__ __forceinline__ void fma4(float4& a, float s, const float4& v) {
    a.x += s * v.x; a.y += s * v.y; a.z += s * v.z; a.w += s * v.w;
}

__device__ __forceinline__ unsigned short f2bf(float f) {
    __hip_bfloat16 h = __float2bfloat16(f);
    return *reinterpret_cast<unsigned short*>(&h);
}
__device__ __forceinline__ float bf2f(unsigned short u) {
    __hip_bfloat16 h = *reinterpret_cast<__hip_bfloat16*>(&u);
    return __bfloat162float(h);
}

// NG = live 8-row groups (wave-uniform). 64-wide d-half contraction, bf16 store.
template<int NG>
__device__ __forceinline__ void compute_store(
    const float* __restrict__ Tc, const float (*__restrict__ Esh)[68],
    const int* __restrict__ Dsh, unsigned short* __restrict__ P,
    const int col0, const int rh, const int my_rows, const int dh)
{
    float4 acc[NG];
    #pragma unroll
    for (int k = 0; k < NG; ++k) acc[k] = make_float4(0.f, 0.f, 0.f, 0.f);

    #pragma unroll 2
    for (int d4 = 0; d4 < 64; d4 += 4) {
        const float* tp = Tc + (size_t)d4 * D;
        const float4 t0 = *(const float4*)(tp);
        const float4 t1 = *(const float4*)(tp + D);
        const float4 t2 = *(const float4*)(tp + 2 * D);
        const float4 t3 = *(const float4*)(tp + 3 * D);
        #pragma unroll
        for (int k = 0; k < NG; ++k) {
            const float4 e = *(const float4*)&Esh[rh + 8 * k][d4];
            fma4(acc[k], e.x, t0); fma4(acc[k], e.y, t1);
            fma4(acc[k], e.z, t2); fma4(acc[k], e.w, t3);
        }
    }

    #pragma unroll
    for (int k = 0; k < NG; ++k) {
        const int r = rh + 8 * k;
        if (r < my_rows) {
            const int row = (Dsh[r] << 1) | dh;
            ushort4 s;
            s.x = f2bf(acc[k].x); s.y = f2bf(acc[k].y);
            s.z = f2bf(acc[k].z); s.w = f2bf(acc[k].w);
            *(ushort4*)(P + (size_t)row * D + col0) = s;
        }
    }
}

// block (u, dh): contraction-half dh of ALL rows of bin u (r14 structure).
// After storing a P row, its designated writer fences (device-scope release)
// and bumps done[b]; the 8th bump queues b; the block scores queued triplets
// after its row loop (reader fence = acquire). Each b scored exactly once,
// fixed read order -> deterministic.
__global__ __launch_bounds__(256) void matvec_kernel(
    const int* __restrict__ idx, const float* __restrict__ ent,
    const float* __restrict__ rel, const float* __restrict__ tt,
    const int* __restrict__ cnt, const int2* __restrict__ rowsbuf,
    unsigned short* __restrict__ P, int* __restrict__ done,
    float* __restrict__ out)
{
    const int u  = blockIdx.x;
    const int dh = blockIdx.y;
    int n_rows = cnt[u];
    if (n_rows == 0) return;
    if (n_rows > CAP_R) n_rows = CAP_R;
    const int base = u * CAP_R;
    const int tid = threadIdx.x;

    const int w    = tid >> 6;             // wave 0..3 -> col slice w*32
    const int lane = tid & 63;
    const int c8   = lane & 7;
    const int rh   = lane >> 3;            // 0..7
    const int col0 = w * 32 + c8 * 4;

    __shared__ float Esh[64][68];          // 17.4 KB
    __shared__ int   Dsh[64];
    __shared__ int   scoreQ[CAP_R];
    __shared__ int   s_qn;
    if (tid == 0) s_qn = 0;
    const float* __restrict__ Tc = tt + (size_t)u * (D * D) + (size_t)dh * 64 * D + col0;

    for (int rr0 = 0; rr0 < n_rows; rr0 += 64) {
        const int my_rows = min(64, n_rows - rr0);

        {   // stage d-half of my_rows entity rows: 4 threads/row, 16 floats each
            const int r = tid >> 2;        // 0..63
            const int q = tid & 3;
            if (r < my_rows) {
                const int2 rec = rowsbuf[base + rr0 + r];
                const float* src = ent + (size_t)rec.x * D + dh * 64 + q * 16;
                const float4 v0 = *(const float4*)(src);
                const float4 v1 = *(const float4*)(src + 4);
                const float4 v2 = *(const float4*)(src + 8);
                const float4 v3 = *(const float4*)(src + 12);
                float* drow = &Esh[r][q * 16];
                *(float4*)(drow)      = v0;
                *(float4*)(drow + 4)  = v1;
                *(float4*)(drow + 8)  = v2;
                *(float4*)(drow + 12) = v3;
                if (q == 0) Dsh[r] = rec.y;
            }
        }
        __syncthreads();

        const int ng = (my_rows + 7) >> 3;   // 1..8, wave-uniform
        switch (ng) {
            case 1: compute_store<1>(Tc, Esh, Dsh, P, col0, rh, my_rows, dh); break;
            case 2: compute_store<2>(Tc, Esh, Dsh, P, col0, rh, my_rows, dh); break;
            case 3: compute_store<3>(Tc, Esh, Dsh, P, col0, rh, my_rows, dh); break;
            case 4: compute_store<4>(Tc, Esh, Dsh, P, col0, rh, my_rows, dh); break;
            case 5: compute_store<5>(Tc, Esh, Dsh, P, col0, rh, my_rows, dh); break;
            case 6: compute_store<6>(Tc, Esh, Dsh, P, col0, rh, my_rows, dh); break;
            case 7: compute_store<7>(Tc, Esh, Dsh, P, col0, rh, my_rows, dh); break;
            default: compute_store<8>(Tc, Esh, Dsh, P, col0, rh, my_rows, dh); break;
        }
        __syncthreads();

        // release: make this block's P stores device-visible, then count rows
        __threadfence();
        if (tid < 64 && (tid & 7) == 0) {      // one thread per row-group lane
            const int rh_ = tid >> 3;
            #pragma unroll
            for (int k = 0; k < 8; ++k) {
                const int r = rh_ + 8 * k;
                if (r < my_rows) {
                    const int b = Dsh[r] >> 2;
                    const int old = atomicAdd(&done[b], 1);
                    if (old == 7) {
                        const int q = atomicAdd(&s_qn, 1);
                        scoreQ[q] = b;
                    }
                }
            }
        }
        __syncthreads();   // protects Esh/Dsh reuse AND publishes scoreQ
    }

    // ---- score queued triplets: one wave per entry ----
    __threadfence();       // acquire: P rows written by other blocks
    const int qn = s_qn;
    for (int qi = w; qi < qn; qi += 4) {
        const int b  = scoreQ[qi];
        const int ri = idx[b * 5 + 1];
        const ushort2* pb = (const ushort2*)(P + (size_t)b * 8 * D);

        float hc0 = 0.f, hc1 = 0.f, tc0 = 0.f, tc1 = 0.f;
        #pragma unroll
        for (int j = 0; j < 4; ++j) {
            const ushort2 vh = pb[j * (D / 2) + lane];
            const ushort2 vt = pb[(4 + j) * (D / 2) + lane];
            hc0 += bf2f(vh.x); hc1 += bf2f(vh.y);
            tc0 += bf2f(vt.x); tc1 += bf2f(vt.y);
        }

        float nh = hc0 * hc0 + hc1 * hc1;
        float nt = tc0 * tc0 + tc1 * tc1;
        #pragma unroll
        for (int off = 32; off; off >>= 1) {
            nh += __shfl_down(nh, off, 64);
            nt += __shfl_down(nt, off, 64);
        }
        nh = __shfl(nh, 0, 64);
        nt = __shfl(nt, 0, 64);
        const float rnh = 1.0f / fmaxf(sqrtf(nh), 1e-12f);
        const float rnt = 1.0f / fmaxf(sqrtf(nt), 1e-12f);

        const float2 rr = *(const float2*)(rel + (size_t)ri * D + lane * 2);
        float v = fabsf(hc0 * rnh + rr.x - tc0 * rnt + 1e-6f)
                + fabsf(hc1 * rnh + rr.y - tc1 * rnt + 1e-6f);
        #pragma unroll
        for (int off = 32; off; off >>= 1) v += __shfl_down(v, off, 64);
        if (lane == 0) out[b] = v;
    }
}

extern "C" void kernel_launch(void* const* d_in, const int* in_sizes, int n_in,
                              void* d_out, int out_size, void* d_ws, size_t ws_size,
                              hipStream_t stream) {
    const int*   idx = (const int*)d_in[0];
    const float* ent = (const float*)d_in[1];
    const float* rel = (const float*)d_in[2];
    const float* tt  = (const float*)d_in[3];
    float* out = (float*)d_out;
    const int B  = in_sizes[0] / 5;
    const int NT = in_sizes[3] / (D * D);   // number of time matrices (1000)

    const size_t CNT_OFF  = 0;
    const size_t DONE_OFF = 8192;
    const size_t ROWS_OFF = (DONE_OFF + (size_t)B * sizeof(int) + 255) & ~(size_t)255;
    const size_t ROWS_BYTES = (size_t)NT * CAP_R * sizeof(int2);
    const size_t P_OFF  = (ROWS_OFF + ROWS_BYTES + 255) & ~(size_t)255;
    const size_t need   = P_OFF + (size_t)B * 8 * D * sizeof(unsigned short);

    if (ws_size < need || NT > 1024) {
        transe_time_kernel<<<dim3(B), dim3(256), 0, stream>>>(idx, ent, rel, tt, out, B);
        return;
    }

    char* ws = (char*)d_ws;
    int*  cnt     = (int*)(ws + CNT_OFF);
    int*  done    = (int*)(ws + DONE_OFF);
    int2* rowsbuf = (int2*)(ws + ROWS_OFF);
    unsigned short* P = (unsigned short*)(ws + P_OFF);

    const int zgrid = (NT + B + 1023) / 1024;
    zero_kernel   <<<dim3(zgrid), dim3(1024), 0, stream>>>(cnt, done, NT, B);
    scatter_kernel<<<dim3(32),    dim3(256),  0, stream>>>(idx, cnt, rowsbuf, B);
    matvec_kernel <<<dim3(NT, 2), dim3(256),  0, stream>>>(idx, ent, rel, tt, cnt, rowsbuf, P, done, out);
}

// Round 16
// 47.409 us; speedup vs baseline: 9.5717x; 9.5717x over previous
//
#include <hip/hip_runtime.h>
#include <hip/hip_bf16.h>

#define D 128
#define CAP_R 128   // max rows per bin (rows = 2*matches; mean 32.8)

// ---------------- fallback (round-1) kernel ----------------
__global__ __launch_bounds__(256) void transe_time_kernel(
    const int* __restrict__ idx, const float* __restrict__ ent,
    const float* __restrict__ rel, const float* __restrict__ tt,
    float* __restrict__ out, int B)
{
    const int b = blockIdx.x;
    if (b >= B) return;
    const int tid = threadIdx.x;
    const int e4  = tid & 31;
    const int g   = tid >> 5;

    __shared__ float sh_h[D];
    __shared__ float sh_t[D];
    __shared__ float ph[8][D];
    __shared__ float pt[8][D];
    __shared__ float wred[8];

    const int hi = idx[b * 5 + 0];
    const int ri = idx[b * 5 + 1];
    const int ti = idx[b * 5 + 2];
    const int si = idx[b * 5 + 3];
    const int ei = idx[b * 5 + 4];

    if (tid < D) {
        sh_h[tid] = ent[(size_t)hi * D + tid];
        sh_t[tid] = ent[(size_t)ti * D + tid];
    }
    __syncthreads();

    const float4* __restrict__ Ts = (const float4*)(tt + (size_t)si * D * D);
    const float4* __restrict__ Te = (const float4*)(tt + (size_t)ei * D * D);

    float4 hacc = make_float4(0.f, 0.f, 0.f, 0.f);
    float4 tacc = make_float4(0.f, 0.f, 0.f, 0.f);

    #pragma unroll 4
    for (int d0 = 0; d0 < D; d0 += 8) {
        const int d = d0 + g;
        const float4 a = Ts[d * 32 + e4];
        const float4 c = Te[d * 32 + e4];
        const float hd = sh_h[d];
        const float td = sh_t[d];
        const float mx = a.x + c.x;
        const float my = a.y + c.y;
        const float mz = a.z + c.z;
        const float mw = a.w + c.w;
        hacc.x += hd * mx; hacc.y += hd * my; hacc.z += hd * mz; hacc.w += hd * mw;
        tacc.x += td * mx; tacc.y += td * my; tacc.z += td * mz; tacc.w += td * mw;
    }

    ((float4*)ph[g])[e4] = hacc;
    ((float4*)pt[g])[e4] = tacc;
    __syncthreads();

    float h2 = 0.f, t2 = 0.f;
    if (tid < D) {
        #pragma unroll
        for (int k = 0; k < 8; ++k) { h2 += ph[k][tid]; t2 += pt[k][tid]; }
    }
    float nh = h2 * h2;
    float nt = t2 * t2;
    #pragma unroll
    for (int off = 32; off; off >>= 1) {
        nh += __shfl_down(nh, off, 64);
        nt += __shfl_down(nt, off, 64);
    }
    const int wv = tid >> 6;
    if ((tid & 63) == 0) { wred[wv * 2] = nh; wred[wv * 2 + 1] = nt; }
    __syncthreads();
    const float NH = wred[0] + wred[2] + wred[4] + wred[6];
    const float NT2 = wred[1] + wred[3] + wred[5] + wred[7];
    const float rnh = 1.0f / fmaxf(sqrtf(NH), 1e-12f);
    const float rnt = 1.0f / fmaxf(sqrtf(NT2), 1e-12f);

    float v = 0.f;
    if (tid < D) {
        const float rr = rel[(size_t)ri * D + tid];
        v = fabsf(h2 * rnh + rr - t2 * rnt + 1e-6f);
    }
    #pragma unroll
    for (int off = 32; off; off >>= 1) v += __shfl_down(v, off, 64);
    __syncthreads();
    if ((tid & 63) == 0) wred[wv] = v;
    __syncthreads();
    if (tid == 0) out[b] = wred[0] + wred[1] + wred[2] + wred[3];
}

// ---------------- binned pipeline: zero -> scatter -> matvec -> score -------

__global__ __launch_bounds__(1024) void zero_cnt_kernel(int* __restrict__ cnt, int NT)
{
    const int t = threadIdx.x;
    if (t < NT) cnt[t] = 0;
}

// rows[u*CAP_R + p] = {eid, y}, y = b*4 + ht*2 + slot
__global__ __launch_bounds__(256) void scatter_kernel(
    const int* __restrict__ idx, int* __restrict__ cnt,
    int2* __restrict__ rowsbuf, int B)
{
    const int i = blockIdx.x * blockDim.x + threadIdx.x;
    const int stride = gridDim.x * blockDim.x;
    for (int b = i; b < B; b += stride) {
        const int h_eid = idx[b * 5 + 0];
        const int t_eid = idx[b * 5 + 2];
        #pragma unroll
        for (int slot = 0; slot < 2; ++slot) {
            const int u = idx[b * 5 + 3 + slot];
            const int p = atomicAdd(&cnt[u], 2);
            if (p + 1 < CAP_R) {
                rowsbuf[u * CAP_R + p]     = make_int2(h_eid, b * 4 + 0 + slot);
                rowsbuf[u * CAP_R + p + 1] = make_int2(t_eid, b * 4 + 2 + slot);
            }
        }
    }
}

__device__ __forceinline__ void fma4(float4& a, float s, const float4& v) {
    a.x += s * v.x; a.y += s * v.y; a.z += s * v.z; a.w += s * v.w;
}

__device__ __forceinline__ unsigned short f2bf(float f) {
    __hip_bfloat16 h = __float2bfloat16(f);
    return *reinterpret_cast<unsigned short*>(&h);
}
__device__ __forceinline__ float bf2f(unsigned short u) {
    __hip_bfloat16 h = *reinterpret_cast<__hip_bfloat16*>(&u);
    return __bfloat162float(h);
}

// NG = live 8-row groups (wave-uniform). 64-wide d-half contraction, bf16 store.
template<int NG>
__device__ __forceinline__ void compute_store(
    const float* __restrict__ Tc, const float (*__restrict__ Esh)[68],
    const int* __restrict__ Dsh, unsigned short* __restrict__ P,
    const int col0, const int rh, const int my_rows, const int dh)
{
    float4 acc[NG];
    #pragma unroll
    for (int k = 0; k < NG; ++k) acc[k] = make_float4(0.f, 0.f, 0.f, 0.f);

    #pragma unroll 2
    for (int d4 = 0; d4 < 64; d4 += 4) {
        const float* tp = Tc + (size_t)d4 * D;
        const float4 t0 = *(const float4*)(tp);
        const float4 t1 = *(const float4*)(tp + D);
        const float4 t2 = *(const float4*)(tp + 2 * D);
        const float4 t3 = *(const float4*)(tp + 3 * D);
        #pragma unroll
        for (int k = 0; k < NG; ++k) {
            const float4 e = *(const float4*)&Esh[rh + 8 * k][d4];
            fma4(acc[k], e.x, t0); fma4(acc[k], e.y, t1);
            fma4(acc[k], e.z, t2); fma4(acc[k], e.w, t3);
        }
    }

    #pragma unroll
    for (int k = 0; k < NG; ++k) {
        const int r = rh + 8 * k;
        if (r < my_rows) {
            const int row = (Dsh[r] << 1) | dh;
            ushort4 s;
            s.x = f2bf(acc[k].x); s.y = f2bf(acc[k].y);
            s.z = f2bf(acc[k].z); s.w = f2bf(acc[k].w);
            *(ushort4*)(P + (size_t)row * D + col0) = s;
        }
    }
}

// block (u, dh): contraction-half dh of ALL rows of bin u (r14 structure).
// No cross-block coordination (r15 lesson: fences/atomics across XCDs = 10x).
__global__ __launch_bounds__(256) void matvec_kernel(
    const float* __restrict__ ent, const float* __restrict__ tt,
    const int* __restrict__ cnt, const int2* __restrict__ rowsbuf,
    unsigned short* __restrict__ P)
{
    const int u  = blockIdx.x;
    const int dh = blockIdx.y;
    int n_rows = cnt[u];
    if (n_rows == 0) return;
    if (n_rows > CAP_R) n_rows = CAP_R;
    const int base = u * CAP_R;
    const int tid = threadIdx.x;

    const int w    = tid >> 6;             // wave 0..3 -> col slice w*32
    const int lane = tid & 63;
    const int c8   = lane & 7;
    const int rh   = lane >> 3;            // 0..7
    const int col0 = w * 32 + c8 * 4;

    __shared__ float Esh[64][68];          // 17.4 KB
    __shared__ int   Dsh[64];
    const float* __restrict__ Tc = tt + (size_t)u * (D * D) + (size_t)dh * 64 * D + col0;

    for (int rr0 = 0; rr0 < n_rows; rr0 += 64) {
        const int my_rows = min(64, n_rows - rr0);

        {   // stage d-half of my_rows entity rows: 4 threads/row, 16 floats each
            const int r = tid >> 2;        // 0..63
            const int q = tid & 3;
            if (r < my_rows) {
                const int2 rec = rowsbuf[base + rr0 + r];
                const float* src = ent + (size_t)rec.x * D + dh * 64 + q * 16;
                const float4 v0 = *(const float4*)(src);
                const float4 v1 = *(const float4*)(src + 4);
                const float4 v2 = *(const float4*)(src + 8);
                const float4 v3 = *(const float4*)(src + 12);
                float* drow = &Esh[r][q * 16];
                *(float4*)(drow)      = v0;
                *(float4*)(drow + 4)  = v1;
                *(float4*)(drow + 8)  = v2;
                *(float4*)(drow + 12) = v3;
                if (q == 0) Dsh[r] = rec.y;
            }
        }
        __syncthreads();

        const int ng = (my_rows + 7) >> 3;   // 1..8, wave-uniform
        switch (ng) {
            case 1: compute_store<1>(Tc, Esh, Dsh, P, col0, rh, my_rows, dh); break;
            case 2: compute_store<2>(Tc, Esh, Dsh, P, col0, rh, my_rows, dh); break;
            case 3: compute_store<3>(Tc, Esh, Dsh, P, col0, rh, my_rows, dh); break;
            case 4: compute_store<4>(Tc, Esh, Dsh, P, col0, rh, my_rows, dh); break;
            case 5: compute_store<5>(Tc, Esh, Dsh, P, col0, rh, my_rows, dh); break;
            case 6: compute_store<6>(Tc, Esh, Dsh, P, col0, rh, my_rows, dh); break;
            case 7: compute_store<7>(Tc, Esh, Dsh, P, col0, rh, my_rows, dh); break;
            default: compute_store<8>(Tc, Esh, Dsh, P, col0, rh, my_rows, dh); break;
        }
        __syncthreads();
    }
}

// P rows per triplet b: b*8 + ht*4 + slot*2 + dh ; h = rows b*8+0..3, t = +4..7
__global__ __launch_bounds__(256) void score_kernel(
    const int* __restrict__ idx, const float* __restrict__ rel,
    const unsigned short* __restrict__ P, float* __restrict__ out, int B)
{
    const int tid = threadIdx.x;
    const int b = blockIdx.x * 4 + (tid >> 6);
    const int l = tid & 63;
    if (b >= B) return;

    const int ri = idx[b * 5 + 1];
    const ushort2* pb = (const ushort2*)(P + (size_t)b * 8 * D);

    float h0 = 0.f, h1 = 0.f, t0 = 0.f, t1 = 0.f;
    #pragma unroll
    for (int j = 0; j < 4; ++j) {
        const ushort2 vh = pb[j * (D / 2) + l];
        const ushort2 vt = pb[(4 + j) * (D / 2) + l];
        h0 += bf2f(vh.x); h1 += bf2f(vh.y);
        t0 += bf2f(vt.x); t1 += bf2f(vt.y);
    }

    float nh = h0 * h0 + h1 * h1;
    float nt = t0 * t0 + t1 * t1;
    #pragma unroll
    for (int off = 32; off; off >>= 1) {
        nh += __shfl_down(nh, off, 64);
        nt += __shfl_down(nt, off, 64);
    }
    nh = __shfl(nh, 0, 64);
    nt = __shfl(nt, 0, 64);
    const float rnh = 1.0f / fmaxf(sqrtf(nh), 1e-12f);
    const float rnt = 1.0f / fmaxf(sqrtf(nt), 1e-12f);

    const float2 rr = *(const float2*)(rel + (size_t)ri * D + l * 2);
    float v = fabsf(h0 * rnh + rr.x - t0 * rnt + 1e-6f)
            + fabsf(h1 * rnh + rr.y - t1 * rnt + 1e-6f);
    #pragma unroll
    for (int off = 32; off; off >>= 1) v += __shfl_down(v, off, 64);
    if (l == 0) out[b] = v;
}

extern "C" void kernel_launch(void* const* d_in, const int* in_sizes, int n_in,
                              void* d_out, int out_size, void* d_ws, size_t ws_size,
                              hipStream_t stream) {
    const int*   idx = (const int*)d_in[0];
    const float* ent = (const float*)d_in[1];
    const float* rel = (const float*)d_in[2];
    const float* tt  = (const float*)d_in[3];
    float* out = (float*)d_out;
    const int B  = in_sizes[0] / 5;
    const int NT = in_sizes[3] / (D * D);   // number of time matrices (1000)

    const size_t CNT_OFF  = 0;
    const size_t ROWS_OFF = 8192;
    const size_t ROWS_BYTES = (size_t)NT * CAP_R * sizeof(int2);
    const size_t P_OFF  = (ROWS_OFF + ROWS_BYTES + 255) & ~(size_t)255;
    const size_t need   = P_OFF + (size_t)B * 8 * D * sizeof(unsigned short);

    if (ws_size < need || NT > 1024) {
        transe_time_kernel<<<dim3(B), dim3(256), 0, stream>>>(idx, ent, rel, tt, out, B);
        return;
    }

    char* ws = (char*)d_ws;
    int*  cnt     = (int*)(ws + CNT_OFF);
    int2* rowsbuf = (int2*)(ws + ROWS_OFF);
    unsigned short* P = (unsigned short*)(ws + P_OFF);

    zero_cnt_kernel<<<dim3(1),           dim3(1024), 0, stream>>>(cnt, NT);
    scatter_kernel <<<dim3(32),          dim3(256),  0, stream>>>(idx, cnt, rowsbuf, B);
    matvec_kernel  <<<dim3(NT, 2),       dim3(256),  0, stream>>>(ent, tt, cnt, rowsbuf, P);
    score_kernel   <<<dim3((B + 3) / 4), dim3(256),  0, stream>>>(idx, rel, P, out, B);
}